// Round 8
// baseline (87.912 us; speedup 1.0000x reference)
//
#include <hip/hip_runtime.h>
#include <hip/hip_bf16.h>

#define MDIM 8192
#define KDIM 512
#define NKT 16   // K-tiles of 32

typedef __attribute__((ext_vector_type(8))) short short8;
typedef __attribute__((ext_vector_type(4))) float f32x4;
typedef __attribute__((ext_vector_type(8))) unsigned short ushort8;

__device__ __forceinline__ unsigned short f32_to_bf16_rne(float f) {
    unsigned int u = __float_as_uint(f);
    u += 0x7FFFu + ((u >> 16) & 1u);
    return (unsigned short)(u >> 16);
}
__device__ __forceinline__ float bf16_to_f32(unsigned short s) {
    return __uint_as_float(((unsigned int)s) << 16);
}

__device__ __forceinline__ void gload16(const void* g, void* l) {
    __builtin_amdgcn_global_load_lds(
        (const __attribute__((address_space(1))) void*)g,
        (__attribute__((address_space(3))) void*)l,
        16, 0, 0);
}

#define BAR()  __builtin_amdgcn_s_barrier()
#define LGK()  do { asm volatile("s_waitcnt lgkmcnt(0)" ::: "memory"); \
                    __builtin_amdgcn_sched_barrier(0); } while (0)
#define VMW0() asm volatile("s_waitcnt vmcnt(0)" ::: "memory")

// Kernel 1: fp32 -> bf16 into ws + sq[row] = sum(bf16(x)^2) (fp32).
__global__ __launch_bounds__(256) void rbf_convert(const float* __restrict__ x,
                                                   unsigned short* __restrict__ xb,
                                                   float* __restrict__ sq) {
    const int lane = threadIdx.x & 63;
    const int wave = threadIdx.x >> 6;
    const int row  = blockIdx.x * 4 + wave;

    const float* xr = x + (size_t)row * KDIM + lane * 8;
    float4 v0 = *(const float4*)(xr);
    float4 v1 = *(const float4*)(xr + 4);
    float vals[8] = {v0.x, v0.y, v0.z, v0.w, v1.x, v1.y, v1.z, v1.w};

    ushort8 packed;
    float s = 0.f;
#pragma unroll
    for (int j = 0; j < 8; ++j) {
        unsigned short b = f32_to_bf16_rne(vals[j]);
        packed[j] = b;
        float f = bf16_to_f32(b);
        s += f * f;
    }
    *(ushort8*)(xb + (size_t)row * KDIM + lane * 8) = packed;

#pragma unroll
    for (int off = 32; off > 0; off >>= 1) s += __shfl_xor(s, off, 64);
    if (lane == 0) sq[row] = s;
}

// triangular XCD-affine enumeration (verified R5/R7): XCD x owns tile-rows
// {4x..4x+3, 60-4x..63-4x} (260 tiles each); band-major sweep.
__device__ __forceinline__ void tile_of(int xcd, int kk, int& tr, int& tc) {
    tr = 0; tc = 0;
    bool found = false;
#pragma unroll 1
    for (int b = 0; b < 8 && !found; ++b) {
#pragma unroll 1
        for (int i = 0; i < 8; ++i) {
            const int rr = (i < 4) ? (4 * xcd + i) : (60 - 4 * xcd + (i - 4));
            int n = rr - 8 * b + 1;
            n = n < 0 ? 0 : (n > 8 ? 8 : n);
            if (kk < n) { tr = rr; tc = 8 * b + kk; found = true; break; }
            kk -= n;
        }
    }
}

// Kernel 2: symmetric RBF, lower-triangle tiles (2080 blocks), 32 KiB LDS as
// TWO 16 KiB buffers (BK=32) -> true double-buffer, 1 raw barrier/iter, no
// vmcnt(0) drains in-loop. 4 blocks/CU. nt stores (load-bearing).
__global__ __launch_bounds__(256, 4) void rbf_gemm(const unsigned short* __restrict__ xb,
                                                   const float* __restrict__ sq,
                                                   float* __restrict__ out) {
    __shared__ char lds[32768];   // [buf][A 8K | B 8K]; epilogue: 4 waves x 8K

    const int t    = threadIdx.x;
    const int lane = t & 63;
    const int wave = t >> 6;
    const int wr   = wave >> 1;   // 0..1
    const int wc   = wave & 1;    // 0..1

    int tr, tc;
    tile_of(blockIdx.x & 7, blockIdx.x >> 3, tr, tc);
    const int brow = tr * 128;
    const int bcol = tc * 128;

    // BK=32 staging: row = t>>2 (64B rows), linear LDS dest slot t&3,
    // global source slot (t&3)^((t>>3)&3) (involution with reader, see below).
    const int srow = t >> 2;                            // 0..63
    const int ssx  = ((t & 3) ^ ((t >> 3) & 3)) * 16;   // swizzled source bytes

    // fragment coords: reader slot = fo ^ ((fr>>1)&3)  (2-way banks = free)
    const int fr = lane & 15;
    const int fo = lane >> 4;
    const int sw = (fr >> 1) & 3;
    const int cx = (fo ^ sw) * 16;
    const int cg = lane >> 4;
    const int cl = lane & 15;

    f32x4 acc[4][4] = {};

    const char* gA = (const char*)xb + (size_t)(brow + srow) * 1024 + ssx;
    const char* gB = (const char*)xb + (size_t)(bcol + srow) * 1024 + ssx;
    char* ldsw = lds + t * 16;   // dest: buf*16384 + {A:0,B:8192} + half*4096 + t*16

    // prologue: stage K-tile 0 into buf 0
    gload16(gA,                       ldsw);
    gload16(gA + 64 * 1024,           ldsw + 4096);
    gload16(gB,                       ldsw + 8192);
    gload16(gB + 64 * 1024,           ldsw + 8192 + 4096);

#pragma unroll 1
    for (int i = 0; i < NKT; ++i) {
        const int cb = i & 1;
        VMW0();            // tile i resident (wave-local; mostly pre-drained)
        BAR();             // all waves: tile i visible, prior reads done
        if (i + 1 < NKT) { // stage tile i+1 into the other buffer
            const size_t ko = (size_t)(i + 1) * 64;
            char* dst = ldsw + (cb ^ 1) * 16384;
            gload16(gA + ko,             dst);
            gload16(gA + 64 * 1024 + ko, dst + 4096);
            gload16(gB + ko,             dst + 8192);
            gload16(gB + 64 * 1024 + ko, dst + 8192 + 4096);
        }
        const char* Ab = lds + cb * 16384;
        const char* Bb = lds + cb * 16384 + 8192;
        short8 a[4], b[4];
#pragma unroll
        for (int m = 0; m < 4; ++m)
            a[m] = *(const short8*)(Ab + (wr * 64 + m * 16 + fr) * 64 + cx);
#pragma unroll
        for (int n = 0; n < 4; ++n)
            b[n] = *(const short8*)(Bb + (wc * 64 + n * 16 + fr) * 64 + cx);
        LGK();
#pragma unroll
        for (int n = 0; n < 4; ++n)
#pragma unroll
            for (int m = 0; m < 4; ++m)
                acc[m][n] = __builtin_amdgcn_mfma_f32_16x16x32_bf16(a[m], b[n], acc[m][n], 0, 0, 0);
    }
    BAR();   // all waves done reading K-buffers before epilogue LDS reuse

    // ---- epilogue (R7-verbatim) ----
    float sqr[16], sqc[4];
#pragma unroll
    for (int m = 0; m < 4; ++m)
#pragma unroll
        for (int j = 0; j < 4; ++j)
            sqr[m * 4 + j] = sq[brow + wr * 64 + m * 16 + cg * 4 + j];
#pragma unroll
    for (int n = 0; n < 4; ++n)
        sqc[n] = sq[bcol + wc * 64 + n * 16 + cl];

#pragma unroll
    for (int m = 0; m < 4; ++m)
#pragma unroll
        for (int n = 0; n < 4; ++n)
#pragma unroll
            for (int j = 0; j < 4; ++j) {
                const float v = fmaf(acc[m][n][j], 1.44269504f,
                                     -0.72134752f * (sqr[m * 4 + j] + sqc[n]));
                acc[m][n][j] = __builtin_exp2f(fminf(v, 0.f));
            }

    // transposed tile (tr!=tc): direct from registers, f32x4 nt stores
    if (tr != tc) {
#pragma unroll
        for (int n = 0; n < 4; ++n) {
            float* orow = out + (size_t)(bcol + wc * 64 + n * 16 + cl) * MDIM
                              + brow + wr * 64 + cg * 4;
#pragma unroll
            for (int m = 0; m < 4; ++m)
                __builtin_nontemporal_store(acc[m][n], (f32x4*)(orow + m * 16));
        }
    }

    // normal tile: per-wave 8 KiB LDS transpose in two 32-row halves
    float* ldsf = (float*)lds + wave * 2048;
    const int col0 = bcol + wc * 64 + cl * 4;
#pragma unroll
    for (int h = 0; h < 2; ++h) {
        asm volatile("" ::: "memory");
#pragma unroll
        for (int mh = 0; mh < 2; ++mh) {
            const int m = h * 2 + mh;
#pragma unroll
            for (int j = 0; j < 4; ++j) {
                const int rl = mh * 16 + cg * 4 + j;
                const int sxr = rl & 7;
#pragma unroll
                for (int n = 0; n < 4; ++n) {
                    const int c = n * 16 + cl;
                    ldsf[rl * 64 + ((((c >> 2) ^ sxr) << 2) | (c & 3))] = acc[m][n][j];
                }
            }
        }
        asm volatile("" ::: "memory");   // per-wave region, in-order DS pipe
#pragma unroll
        for (int k = 0; k < 8; ++k) {
            const int rl = k * 4 + cg;
            f32x4 v = *(const f32x4*)&ldsf[rl * 64 + ((cl ^ (rl & 7)) << 2)];
            const int row = brow + wr * 64 + h * 32 + rl;
            __builtin_nontemporal_store(v, (f32x4*)(out + (size_t)row * MDIM + col0));
        }
        asm volatile("" ::: "memory");   // reads precede next half's overwrites
    }
}

extern "C" void kernel_launch(void* const* d_in, const int* in_sizes, int n_in,
                              void* d_out, int out_size, void* d_ws, size_t ws_size,
                              hipStream_t stream) {
    const float* x = (const float*)d_in[0];
    float* out = (float*)d_out;

    float* sq = (float*)d_ws;
    unsigned short* xb = (unsigned short*)((char*)d_ws + MDIM * sizeof(float));

    rbf_convert<<<MDIM / 4, 256, 0, stream>>>(x, xb, sq);
    rbf_gemm<<<dim3(2080), 256, 0, stream>>>(xb, sq, out);
}

// Round 9
// 82.262 us; speedup vs baseline: 1.0687x; 1.0687x over previous
//
#include <hip/hip_runtime.h>
#include <hip/hip_bf16.h>

#define MDIM 8192
#define KDIM 512
#define NKT 16   // K-tiles of 32

typedef __attribute__((ext_vector_type(8))) short short8;
typedef __attribute__((ext_vector_type(4))) float f32x4;
typedef __attribute__((ext_vector_type(8))) unsigned short ushort8;

__device__ __forceinline__ unsigned short f32_to_bf16_rne(float f) {
    unsigned int u = __float_as_uint(f);
    u += 0x7FFFu + ((u >> 16) & 1u);
    return (unsigned short)(u >> 16);
}
__device__ __forceinline__ float bf16_to_f32(unsigned short s) {
    return __uint_as_float(((unsigned int)s) << 16);
}

__device__ __forceinline__ void gload16(const void* g, void* l) {
    __builtin_amdgcn_global_load_lds(
        (const __attribute__((address_space(1))) void*)g,
        (__attribute__((address_space(3))) void*)l,
        16, 0, 0);
}

#define BAR()  __builtin_amdgcn_s_barrier()
#define LGK()  do { asm volatile("s_waitcnt lgkmcnt(0)" ::: "memory"); \
                    __builtin_amdgcn_sched_barrier(0); } while (0)
#define VMW0() asm volatile("s_waitcnt vmcnt(0)" ::: "memory")

// Kernel 1: fp32 -> bf16 into ws + sq[row] = sum(bf16(x)^2) (fp32).
__global__ __launch_bounds__(256) void rbf_convert(const float* __restrict__ x,
                                                   unsigned short* __restrict__ xb,
                                                   float* __restrict__ sq) {
    const int lane = threadIdx.x & 63;
    const int wave = threadIdx.x >> 6;
    const int row  = blockIdx.x * 4 + wave;

    const float* xr = x + (size_t)row * KDIM + lane * 8;
    float4 v0 = *(const float4*)(xr);
    float4 v1 = *(const float4*)(xr + 4);
    float vals[8] = {v0.x, v0.y, v0.z, v0.w, v1.x, v1.y, v1.z, v1.w};

    ushort8 packed;
    float s = 0.f;
#pragma unroll
    for (int j = 0; j < 8; ++j) {
        unsigned short b = f32_to_bf16_rne(vals[j]);
        packed[j] = b;
        float f = bf16_to_f32(b);
        s += f * f;
    }
    *(ushort8*)(xb + (size_t)row * KDIM + lane * 8) = packed;

#pragma unroll
    for (int off = 32; off > 0; off >>= 1) s += __shfl_xor(s, off, 64);
    if (lane == 0) sq[row] = s;
}

// triangular XCD-affine enumeration (verified R5/R7): XCD x owns tile-rows
// {4x..4x+3, 60-4x..63-4x} (260 tiles each); band-major sweep.
__device__ __forceinline__ void tile_of(int xcd, int kk, int& tr, int& tc) {
    tr = 0; tc = 0;
    bool found = false;
#pragma unroll 1
    for (int b = 0; b < 8 && !found; ++b) {
#pragma unroll 1
        for (int i = 0; i < 8; ++i) {
            const int rr = (i < 4) ? (4 * xcd + i) : (60 - 4 * xcd + (i - 4));
            int n = rr - 8 * b + 1;
            n = n < 0 ? 0 : (n > 8 ? 8 : n);
            if (kk < n) { tr = rr; tc = 8 * b + kk; found = true; break; }
            kk -= n;
        }
    }
}

// Kernel 2: symmetric RBF, lower-triangle tiles (2080 blocks), R8 K-loop
// (BK=32 double-buffer, 4 blocks/CU) + NEW block-cooperative epilogue:
// 32 KiB [64][128]f32 transpose buffer -> 512B-contiguous nt store segments
// for BOTH the normal and transposed tiles (was 256B / 64B).
__global__ __launch_bounds__(256, 4) void rbf_gemm(const unsigned short* __restrict__ xb,
                                                   const float* __restrict__ sq,
                                                   float* __restrict__ out) {
    __shared__ char lds[32768];   // K-loop: [buf][A 8K | B 8K]; epilogue: [64][128] f32

    const int t    = threadIdx.x;
    const int lane = t & 63;
    const int wave = t >> 6;
    const int wr   = wave >> 1;   // 0..1
    const int wc   = wave & 1;    // 0..1

    int tr, tc;
    tile_of(blockIdx.x & 7, blockIdx.x >> 3, tr, tc);
    const int brow = tr * 128;
    const int bcol = tc * 128;

    // BK=32 staging: row = t>>2 (64B rows), linear LDS dest slot t&3,
    // global source slot (t&3)^((t>>3)&3) (involution with reader, verified R8).
    const int srow = t >> 2;                            // 0..63
    const int ssx  = ((t & 3) ^ ((t >> 3) & 3)) * 16;   // swizzled source bytes

    // fragment coords: reader slot = fo ^ ((fr>>1)&3)  (2-way banks = free)
    const int fr = lane & 15;
    const int fo = lane >> 4;
    const int sw = (fr >> 1) & 3;
    const int cx = (fo ^ sw) * 16;
    const int cg = lane >> 4;
    const int cl = lane & 15;

    f32x4 acc[4][4] = {};

    const char* gA = (const char*)xb + (size_t)(brow + srow) * 1024 + ssx;
    const char* gB = (const char*)xb + (size_t)(bcol + srow) * 1024 + ssx;
    char* ldsw = lds + t * 16;   // dest: buf*16384 + {A:0,B:8192} + half*4096 + t*16

    // prologue: stage K-tile 0 into buf 0
    gload16(gA,             ldsw);
    gload16(gA + 64 * 1024, ldsw + 4096);
    gload16(gB,             ldsw + 8192);
    gload16(gB + 64 * 1024, ldsw + 8192 + 4096);

#pragma unroll 1
    for (int i = 0; i < NKT; ++i) {
        const int cb = i & 1;
        VMW0();            // tile i resident (wave-local; mostly pre-drained)
        BAR();             // all waves: tile i visible, prior reads done
        if (i + 1 < NKT) { // stage tile i+1 into the other buffer
            const size_t ko = (size_t)(i + 1) * 64;
            char* dst = ldsw + (cb ^ 1) * 16384;
            gload16(gA + ko,             dst);
            gload16(gA + 64 * 1024 + ko, dst + 4096);
            gload16(gB + ko,             dst + 8192);
            gload16(gB + 64 * 1024 + ko, dst + 8192 + 4096);
        }
        const char* Ab = lds + cb * 16384;
        const char* Bb = lds + cb * 16384 + 8192;
        short8 a[4], b[4];
#pragma unroll
        for (int m = 0; m < 4; ++m)
            a[m] = *(const short8*)(Ab + (wr * 64 + m * 16 + fr) * 64 + cx);
#pragma unroll
        for (int n = 0; n < 4; ++n)
            b[n] = *(const short8*)(Bb + (wc * 64 + n * 16 + fr) * 64 + cx);
        LGK();
#pragma unroll
        for (int n = 0; n < 4; ++n)
#pragma unroll
            for (int m = 0; m < 4; ++m)
                acc[m][n] = __builtin_amdgcn_mfma_f32_16x16x32_bf16(a[m], b[n], acc[m][n], 0, 0, 0);
    }

    // ---- epilogue ----
    float sqr[16], sqc[4];
#pragma unroll
    for (int m = 0; m < 4; ++m)
#pragma unroll
        for (int j = 0; j < 4; ++j)
            sqr[m * 4 + j] = sq[brow + wr * 64 + m * 16 + cg * 4 + j];
#pragma unroll
    for (int n = 0; n < 4; ++n)
        sqc[n] = sq[bcol + wc * 64 + n * 16 + cl];

#pragma unroll
    for (int m = 0; m < 4; ++m)
#pragma unroll
        for (int n = 0; n < 4; ++n)
#pragma unroll
            for (int j = 0; j < 4; ++j) {
                const float v = fmaf(acc[m][n][j], 1.44269504f,
                                     -0.72134752f * (sqr[m * 4 + j] + sqc[n]));
                acc[m][n][j] = __builtin_exp2f(fminf(v, 0.f));
            }

    // Block-cooperative transpose buffer: T = [64 rows][128 cols] f32 (32 KB),
    // XOR-swizzled at 16B-group granularity: physical group = g ^ ((row>>2)&7).
    float* T = (float*)lds;
    const int rlane = lane >> 5;    // read phase: sub-row 0/1
    const int lg    = lane & 31;    // read phase: logical 16B group 0..31

    // ---- normal tile, two 64-row halves (half h written by waves wr==h) ----
#pragma unroll
    for (int h = 0; h < 2; ++h) {
        __syncthreads();           // T free (K-loop reads / prior phase done)
        if (wr == h) {
#pragma unroll
            for (int m = 0; m < 4; ++m)
#pragma unroll
                for (int j = 0; j < 4; ++j) {
                    const int r = m * 16 + cg * 4 + j;
                    const int X = (r >> 2) & 7;
#pragma unroll
                    for (int n = 0; n < 4; ++n) {
                        const int g = wc * 16 + n * 4 + (cl >> 2);
                        T[r * 128 + ((g ^ X) << 2) + (cl & 3)] = acc[m][n][j];
                    }
                }
        }
        __syncthreads();
        // all waves: wave w streams rows w*16..w*16+15; 2 rows x 512B per instr
#pragma unroll
        for (int k = 0; k < 8; ++k) {
            const int r = wave * 16 + k * 2 + rlane;
            f32x4 v = *(const f32x4*)&T[r * 128 + ((lg ^ ((r >> 2) & 7)) << 2)];
            const size_t row = (size_t)(brow + h * 64 + r);
            __builtin_nontemporal_store(v, (f32x4*)(out + row * MDIM + bcol + lg * 4));
        }
    }

    // ---- transposed tile (tr!=tc), two 64-row halves keyed by wc ----
    if (tr != tc) {
#pragma unroll
        for (int h = 0; h < 2; ++h) {
            __syncthreads();
            if (wc == h) {
#pragma unroll
                for (int n = 0; n < 4; ++n) {
                    const int cr = n * 16 + cl;          // T-row (out row bcol+h*64+cr)
                    const int X  = (cr >> 2) & 7;
#pragma unroll
                    for (int m = 0; m < 4; ++m) {
                        const int g = wr * 16 + m * 4 + cg;   // 16B group along out-col
                        *(f32x4*)&T[cr * 128 + ((g ^ X) << 2)] = acc[m][n];  // j-contig
                    }
                }
            }
            __syncthreads();
#pragma unroll
            for (int k = 0; k < 8; ++k) {
                const int cr = wave * 16 + k * 2 + rlane;
                f32x4 v = *(const f32x4*)&T[cr * 128 + ((lg ^ ((cr >> 2) & 7)) << 2)];
                const size_t row = (size_t)(bcol + h * 64 + cr);
                __builtin_nontemporal_store(v, (f32x4*)(out + row * MDIM + brow + lg * 4));
            }
        }
    }
}

extern "C" void kernel_launch(void* const* d_in, const int* in_sizes, int n_in,
                              void* d_out, int out_size, void* d_ws, size_t ws_size,
                              hipStream_t stream) {
    const float* x = (const float*)d_in[0];
    float* out = (float*)d_out;

    float* sq = (float*)d_ws;
    unsigned short* xb = (unsigned short*)((char*)d_ws + MDIM * sizeof(float));

    rbf_convert<<<MDIM / 4, 256, 0, stream>>>(x, xb, sq);
    rbf_gemm<<<dim3(2080), 256, 0, stream>>>(xb, sq, out);
}